// Round 1
// baseline (2963.497 us; speedup 1.0000x reference)
//
#include <hip/hip_runtime.h>

// SpatialAttentionLSTMDecoder on MI355X (gfx950).
// B=128, T=32, V=10000, F=H=768, R=49.
// Strategy: f16 MFMA (16x16x32) for all GEMMs, fp32 recurrence state.
// Phase A: convert weights to f16, gather emb, feat_proj GEMM.
// Loop: [lstm(t-1)] -> hWh GEMM -> fused attention -> gates GEMM (split-K 3).
// End: lstm(31), big fc GEMM (4096x10000x768) with bias + (b,t) remap, tail copy.

typedef _Float16 f16x8 __attribute__((ext_vector_type(8)));
typedef float f32x4 __attribute__((ext_vector_type(4)));

#define NB 128
#define NT 32
#define NV 10000
#define NH 768
#define NR 49
#define OUT_ELEMS 40960000  // B*T*V

__device__ __forceinline__ float fast_tanh(float x) {
  x = fminf(9.f, fmaxf(-9.f, x));
  float e = __expf(2.f * x);
  return (e - 1.f) / (e + 1.f);
}
__device__ __forceinline__ float sigm(float x) { return 1.f / (1.f + __expf(-x)); }

__device__ __forceinline__ void gld16(const void* g, void* l) {
  __builtin_amdgcn_global_load_lds((const __attribute__((address_space(1))) void*)g,
                                   (__attribute__((address_space(3))) void*)l, 16, 0, 0);
}

// ---------------- generic f16 MFMA GEMM ----------------
// C[m][n] = sum_k A[m][k] * Bt[n][k]   (A: MxK row-major lda, Bt: NxK row-major ldb)
// EPI 0: C fp32 (M,N) plain.  EPI 1: partial, C += z*M*N.  EPI 2: fc epilogue:
//   row r=t*128+b -> out[(b*32+t)*NV + n] = acc + bias[n], guard n<N.
template <int BM, int BN, int EPI>
__global__ __launch_bounds__(256) void gemm_f16(
    const _Float16* __restrict__ A, int lda,
    const _Float16* __restrict__ Bt, int ldb,
    float* __restrict__ C, const float* __restrict__ bias,
    int M, int N, int ksteps, int ksplit) {
  constexpr int BK = 64;
  __shared__ __attribute__((aligned(16))) _Float16 sA[BM * BK];
  __shared__ __attribute__((aligned(16))) _Float16 sB[BN * BK];
  const int tid = threadIdx.x;
  const int m0 = blockIdx.x * BM, n0 = blockIdx.y * BN;
  const int z = blockIdx.z;
  A += (size_t)z * ksplit;
  Bt += (size_t)z * ksplit;
  if (EPI == 1) C += (size_t)z * M * N;

  constexpr int WM = BM / 2, WN = BN / 2;
  constexpr int MF = WM / 16, NF = WN / 16;
  const int wid = tid >> 6, lane = tid & 63;
  const int wr = wid >> 1, wc = wid & 1;
  const int lr = lane & 15;
  const int lk = (lane >> 4) * 8;

  f32x4 acc[MF][NF] = {};

  for (int kt = 0; kt < ksteps; ++kt) {
    const int kbase = kt * BK;
#pragma unroll
    for (int i = 0; i < BM / 32; i++) {
      int idx = tid + i * 256;
      int row = idx >> 3, seg = idx & 7;
      gld16(A + (size_t)(m0 + row) * lda + kbase + seg * 8, sA + idx * 8);
    }
#pragma unroll
    for (int i = 0; i < BN / 32; i++) {
      int idx = tid + i * 256;
      int row = idx >> 3, seg = idx & 7;
      int gr = n0 + row;
      if (gr >= N) gr = N - 1;  // only possible for EPI==2 (N=10000)
      gld16(Bt + (size_t)gr * ldb + kbase + seg * 8, sB + idx * 8);
    }
    __syncthreads();
#pragma unroll
    for (int kk = 0; kk < 2; ++kk) {
      f16x8 af[MF], bf[NF];
#pragma unroll
      for (int m = 0; m < MF; m++)
        af[m] = *(const f16x8*)&sA[(wr * WM + m * 16 + lr) * BK + kk * 32 + lk];
#pragma unroll
      for (int n = 0; n < NF; n++)
        bf[n] = *(const f16x8*)&sB[(wc * WN + n * 16 + lr) * BK + kk * 32 + lk];
#pragma unroll
      for (int m = 0; m < MF; m++)
#pragma unroll
        for (int n = 0; n < NF; n++)
          acc[m][n] = __builtin_amdgcn_mfma_f32_16x16x32_f16(af[m], bf[n], acc[m][n], 0, 0, 0);
    }
    __syncthreads();
  }

  const int rowb = (lane >> 4) * 4;
#pragma unroll
  for (int m = 0; m < MF; m++) {
    int gm = m0 + wr * WM + m * 16 + rowb;
#pragma unroll
    for (int n = 0; n < NF; n++) {
      int gn = n0 + wc * WN + n * 16 + lr;
#pragma unroll
      for (int j = 0; j < 4; j++) {
        int r = gm + j;
        if (EPI == 2) {
          if (gn < N) {
            int t = r >> 7, b = r & 127;
            C[((size_t)(b * NT + t)) * NV + gn] = acc[m][n][j] + bias[gn];
          }
        } else {
          C[(size_t)r * N + gn] = acc[m][n][j];
        }
      }
    }
  }
}

// ---------------- small kernels ----------------
__global__ void k_f32_to_f16(const float* __restrict__ src, _Float16* __restrict__ dst, int n) {
  int i = blockIdx.x * 256 + threadIdx.x;
  if (i < n) dst[i] = (_Float16)src[i];
}

// Wcat (3072 x 2304) = [W_ih (3072x1536) | W_hh (3072x768)]
__global__ void k_wcat(const float* __restrict__ W_ih, const float* __restrict__ W_hh,
                       _Float16* __restrict__ Wcat) {
  int j = blockIdx.x;
  int k = blockIdx.y * 256 + threadIdx.x;
  float v = (k < 1536) ? W_ih[(size_t)j * 1536 + k] : W_hh[(size_t)j * 768 + (k - 1536)];
  Wcat[(size_t)j * 2304 + k] = (_Float16)v;
}

// emb slots of A_all: A_all[t][b][0:768] = emb_W[captions[b,t]]
__global__ void k_emb(const int* __restrict__ captions, const float* __restrict__ emb_W,
                      _Float16* __restrict__ A_all) {
  int bt = blockIdx.x;  // b*32+t
  int k = blockIdx.y * 256 + threadIdx.x;
  int b = bt >> 5, t = bt & 31;
  int tok = captions[bt];
  A_all[(size_t)t * (NB * 2304) + (size_t)b * 2304 + k] = (_Float16)emb_W[(size_t)tok * NH + k];
}

// h0 = tanh(mean_r features), c0 = 0; write h0 f16 into A_all[0] h-slot
__global__ void k_init(const float* __restrict__ features, float* __restrict__ h,
                       float* __restrict__ c, _Float16* __restrict__ A_all) {
  int b = blockIdx.x;
  int f = blockIdx.y * 256 + threadIdx.x;
  float s = 0.f;
#pragma unroll 7
  for (int r = 0; r < NR; r++) s += features[((size_t)(b * NR + r)) * NH + f];
  float h0 = tanhf(s * (1.f / 49.f));
  h[b * NH + f] = h0;
  c[b * NH + f] = 0.f;
  A_all[(size_t)b * 2304 + 1536 + f] = (_Float16)h0;
}

// fused attention for one timestep: scores->softmax->context (writes f16 ctx slot)
__global__ __launch_bounds__(256) void k_attn(
    const float* __restrict__ feat_proj, const float* __restrict__ hWh,
    const float* __restrict__ attn_b, const float* __restrict__ v,
    const float* __restrict__ features, _Float16* __restrict__ ctx_out) {
  __shared__ float hw[NH], vv[NH], sc[NR], al[NR];
  int b = blockIdx.x, tid = threadIdx.x;
  for (int i = tid; i < NH; i += 256) {
    hw[i] = hWh[b * NH + i] + hWh[NB * NH + b * NH + i] + attn_b[i];  // sum 2 split-K parts
    vv[i] = v[i];
  }
  __syncthreads();
  int wid = tid >> 6, lane = tid & 63;
  for (int r = wid; r < NR; r += 4) {
    const float* fp = feat_proj + ((size_t)(b * NR + r)) * NH;
    float s = 0.f;
    for (int hh = lane; hh < NH; hh += 64) s += fast_tanh(fp[hh] + hw[hh]) * vv[hh];
#pragma unroll
    for (int off = 32; off; off >>= 1) s += __shfl_down(s, off);
    if (lane == 0) sc[r] = s;
  }
  __syncthreads();
  if (tid < 64) {
    float s = (tid < NR) ? sc[tid] : -1e30f;
    float m = s;
#pragma unroll
    for (int off = 32; off; off >>= 1) m = fmaxf(m, __shfl_xor(m, off));
    float e = (tid < NR) ? __expf(s - m) : 0.f;
    float sum = e;
#pragma unroll
    for (int off = 32; off; off >>= 1) sum += __shfl_xor(sum, off);
    if (tid < NR) al[tid] = e / sum;
  }
  __syncthreads();
  for (int f = tid; f < NH; f += 256) {
    float acc = 0.f;
#pragma unroll 7
    for (int r = 0; r < NR; r++) acc += al[r] * features[((size_t)(b * NR + r)) * NH + f];
    ctx_out[(size_t)b * 2304 + f] = (_Float16)acc;
  }
}

// LSTM elementwise: sum 3 gate partials + biases, update c,h; write h f16 to H_all and A_all[t+1]
__global__ void k_lstm(const float* __restrict__ gp, const float* __restrict__ b_ih,
                       const float* __restrict__ b_hh, float* __restrict__ h,
                       float* __restrict__ c, _Float16* __restrict__ H_all_t,
                       _Float16* __restrict__ A_next) {
  int b = blockIdx.x;
  int hh = blockIdx.y * 256 + threadIdx.x;
  float gi = 0, gf = 0, gg = 0, go = 0;
#pragma unroll
  for (int z = 0; z < 3; z++) {
    const float* g = gp + (size_t)z * (NB * 3072) + (size_t)b * 3072;
    gi += g[hh];
    gf += g[hh + 768];
    gg += g[hh + 1536];
    go += g[hh + 2304];
  }
  gi += b_ih[hh] + b_hh[hh];
  gf += b_ih[768 + hh] + b_hh[768 + hh];
  gg += b_ih[1536 + hh] + b_hh[1536 + hh];
  go += b_ih[2304 + hh] + b_hh[2304 + hh];
  float i_ = sigm(gi), f_ = sigm(gf), g_ = fast_tanh(gg), o_ = sigm(go);
  float cn = f_ * c[b * NH + hh] + i_ * g_;
  float hn = o_ * fast_tanh(cn);
  c[b * NH + hh] = cn;
  h[b * NH + hh] = hn;
  H_all_t[(size_t)b * NH + hh] = (_Float16)hn;
  if (A_next) A_next[(size_t)b * 2304 + hh] = (_Float16)hn;
}

__global__ void k_tail(const float* __restrict__ h, const float* __restrict__ c,
                       float* __restrict__ out) {
  int i = blockIdx.x * 256 + threadIdx.x;  // 98304
  out[OUT_ELEMS + i] = h[i];
  out[OUT_ELEMS + NB * NH + i] = c[i];
}

// ---------------- host ----------------
extern "C" void kernel_launch(void* const* d_in, const int* in_sizes, int n_in,
                              void* d_out, int out_size, void* d_ws, size_t ws_size,
                              hipStream_t stream) {
  const float* features = (const float*)d_in[0];
  const int* captions = (const int*)d_in[1];
  const float* emb_W = (const float*)d_in[2];
  const float* attn_W = (const float*)d_in[3];
  const float* attn_b = (const float*)d_in[4];
  const float* attnv_W = (const float*)d_in[5];
  // d_in[6] attnv_b: constant shift, cancels in softmax
  const float* W_ih = (const float*)d_in[7];
  const float* W_hh = (const float*)d_in[8];
  const float* b_ih = (const float*)d_in[9];
  const float* b_hh = (const float*)d_in[10];
  const float* fc_W = (const float*)d_in[11];
  const float* fc_b = (const float*)d_in[12];
  float* out = (float*)d_out;

  char* p = (char*)d_ws;
  _Float16* A_all = (_Float16*)p;  p += 18874368;   // (T,B,2304) f16: [emb|ctx|h]
  _Float16* H_all = (_Float16*)p;  p += 6291456;    // (T,B,768) f16
  _Float16* feat16 = (_Float16*)p; p += 9633792;    // features f16 (6272,768)
  _Float16* attnW16 = (_Float16*)p; p += 2359296;   // attn_W f16 (768,1536)
  _Float16* Wcat16 = (_Float16*)p; p += 14155776;   // (3072,2304) f16
  _Float16* fcW16 = (_Float16*)p;  p += 15360000;   // (10000,768) f16
  float* feat_proj = (float*)p;    p += 19267584;   // (6272,768) f32
  float* hWhbuf = (float*)p;       p += 786432;     // 2 split-K partials (128,768)
  float* gates_p = (float*)p;      p += 4718592;    // 3 partials (128,3072)
  float* hbuf = (float*)p;         p += 393216;
  float* cbuf = (float*)p;         p += 393216;

  const size_t BA = (size_t)NB * 2304;  // A_all elems per timestep

  // phase A: conversions
  k_f32_to_f16<<<dim3(18816), 256, 0, stream>>>(features, feat16, 4816896);
  k_f32_to_f16<<<dim3(4608), 256, 0, stream>>>(attn_W, attnW16, 1179648);
  k_f32_to_f16<<<dim3(30000), 256, 0, stream>>>(fc_W, fcW16, 7680000);
  k_wcat<<<dim3(3072, 9), 256, 0, stream>>>(W_ih, W_hh, Wcat16);
  k_emb<<<dim3(4096, 3), 256, 0, stream>>>(captions, emb_W, A_all);
  k_init<<<dim3(128, 3), 256, 0, stream>>>(features, hbuf, cbuf, A_all);
  // feat_proj = features @ Wf.T  (6272x768, K=768)
  gemm_f16<128, 128, 0><<<dim3(49, 6, 1), 256, 0, stream>>>(
      feat16, 768, attnW16, 1536, feat_proj, nullptr, 6272, 768, 12, 0);

  // sequential scan
  for (int t = 0; t < NT; t++) {
    if (t > 0)
      k_lstm<<<dim3(128, 3), 256, 0, stream>>>(gates_p, b_ih, b_hh, hbuf, cbuf,
                                               H_all + (size_t)(t - 1) * NB * NH,
                                               A_all + (size_t)t * BA + 1536);
    // hWh = h @ Wh.T (128x768, K=768, split-K 2)
    gemm_f16<64, 64, 1><<<dim3(2, 12, 2), 256, 0, stream>>>(
        A_all + (size_t)t * BA + 1536, 2304, attnW16 + 768, 1536, hWhbuf, nullptr,
        128, 768, 6, 384);
    k_attn<<<dim3(128), 256, 0, stream>>>(feat_proj, hWhbuf, attn_b, attnv_W, features,
                                          A_all + (size_t)t * BA + 768);
    // gates = [emb|ctx|h] @ Wcat.T (128x3072, K=2304, split-K 3)
    gemm_f16<64, 64, 1><<<dim3(2, 48, 3), 256, 0, stream>>>(
        A_all + (size_t)t * BA, 2304, Wcat16, 2304, gates_p, nullptr, 128, 3072, 12, 768);
  }
  k_lstm<<<dim3(128, 3), 256, 0, stream>>>(gates_p, b_ih, b_hh, hbuf, cbuf,
                                           H_all + (size_t)(NT - 1) * NB * NH, nullptr);
  // fc: outputs = H_all @ fc_W.T + fc_b  (4096x10000, K=768)
  gemm_f16<128, 128, 2><<<dim3(32, 79, 1), 256, 0, stream>>>(
      H_all, 768, fcW16, 768, out, fc_b, 4096, 10000, 12, 0);
  k_tail<<<dim3(384), 256, 0, stream>>>(hbuf, cbuf, out);
}

// Round 2
// 1131.616 us; speedup vs baseline: 2.6188x; 2.6188x over previous
//
#include <hip/hip_runtime.h>

// SpatialAttentionLSTMDecoder on MI355X (gfx950). B=128,T=32,V=10000,F=H=768,R=49.
// R2: f16 everywhere for streamed data, emb-gates hoisted out of loop,
// attention split into wide scores kernel + ctx kernel, per-step GEMMs K=768.

typedef _Float16 f16x8 __attribute__((ext_vector_type(8)));
typedef _Float16 f16x4 __attribute__((ext_vector_type(4)));
typedef float f32x4 __attribute__((ext_vector_type(4)));

#define NB 128
#define NT 32
#define NV 10000
#define NH 768
#define NR 49
#define OUT_ELEMS 40960000  // B*T*V

__device__ __forceinline__ float fast_tanh(float x) {
  x = fminf(9.f, fmaxf(-9.f, x));
  float e = __expf(2.f * x);
  return (e - 1.f) / (e + 1.f);
}
__device__ __forceinline__ float sigm(float x) { return 1.f / (1.f + __expf(-x)); }

__device__ __forceinline__ void gld16(const void* g, void* l) {
  __builtin_amdgcn_global_load_lds((const __attribute__((address_space(1))) void*)g,
                                   (__attribute__((address_space(3))) void*)l, 16, 0, 0);
}

// ---------------- generic f16 MFMA GEMM (16x16x32) ----------------
// C[m][n] = sum_k A[m][k]*Bt[n][k]. A: MxK lda, Bt: NxK ldb (both f16 row-major).
// EPI 1: f32 partials, C += z*M*N.
// EPI 2: fc epilogue: row r -> out[((r&127)*32 + (r>>7))*NV + n] = acc + bias[n], n<N guard.
// EPI 3: f16 out with bias add.
// EPI 4: f16 out plain.
template <int BM, int BN, int EPI>
__global__ __launch_bounds__(256) void gemm_f16(
    const _Float16* __restrict__ A, int lda,
    const _Float16* __restrict__ Bt, int ldb,
    void* __restrict__ Cv, const float* __restrict__ bias,
    int M, int N, int ksteps, int ksplit) {
  constexpr int BK = 64;
  __shared__ __attribute__((aligned(16))) _Float16 sA[BM * BK];
  __shared__ __attribute__((aligned(16))) _Float16 sB[BN * BK];
  const int tid = threadIdx.x;
  const int m0 = blockIdx.x * BM, n0 = blockIdx.y * BN;
  const int z = blockIdx.z;
  A += (size_t)z * ksplit;
  Bt += (size_t)z * ksplit;

  constexpr int WM = BM / 2, WN = BN / 2;
  constexpr int MF = WM / 16, NF = WN / 16;
  const int wid = tid >> 6, lane = tid & 63;
  const int wr = wid >> 1, wc = wid & 1;
  const int lr = lane & 15;
  const int lk = (lane >> 4) * 8;

  f32x4 acc[MF][NF] = {};

  for (int kt = 0; kt < ksteps; ++kt) {
    const int kbase = kt * BK;
#pragma unroll
    for (int i = 0; i < BM / 32; i++) {
      int idx = tid + i * 256;
      int row = idx >> 3, seg = idx & 7;
      gld16(A + (size_t)(m0 + row) * lda + kbase + seg * 8, sA + idx * 8);
    }
#pragma unroll
    for (int i = 0; i < BN / 32; i++) {
      int idx = tid + i * 256;
      int row = idx >> 3, seg = idx & 7;
      int gr = n0 + row;
      if (gr >= N) gr = N - 1;  // only possible for EPI==2 (N=10000)
      gld16(Bt + (size_t)gr * ldb + kbase + seg * 8, sB + idx * 8);
    }
    __syncthreads();
#pragma unroll
    for (int kk = 0; kk < 2; ++kk) {
      f16x8 af[MF], bf[NF];
#pragma unroll
      for (int m = 0; m < MF; m++)
        af[m] = *(const f16x8*)&sA[(wr * WM + m * 16 + lr) * BK + kk * 32 + lk];
#pragma unroll
      for (int n = 0; n < NF; n++)
        bf[n] = *(const f16x8*)&sB[(wc * WN + n * 16 + lr) * BK + kk * 32 + lk];
#pragma unroll
      for (int m = 0; m < MF; m++)
#pragma unroll
        for (int n = 0; n < NF; n++)
          acc[m][n] = __builtin_amdgcn_mfma_f32_16x16x32_f16(af[m], bf[n], acc[m][n], 0, 0, 0);
    }
    __syncthreads();
  }

  const int rowb = (lane >> 4) * 4;
#pragma unroll
  for (int m = 0; m < MF; m++) {
    int gm = m0 + wr * WM + m * 16 + rowb;
#pragma unroll
    for (int n = 0; n < NF; n++) {
      int gn = n0 + wc * WN + n * 16 + lr;
#pragma unroll
      for (int j = 0; j < 4; j++) {
        int r = gm + j;
        if (EPI == 1) {
          float* C = (float*)Cv + (size_t)z * M * N;
          C[(size_t)r * N + gn] = acc[m][n][j];
        } else if (EPI == 2) {
          if (gn < N) {
            int t = r >> 7, b = r & 127;
            ((float*)Cv)[((size_t)(b * NT + t)) * NV + gn] = acc[m][n][j] + bias[gn];
          }
        } else if (EPI == 3) {
          ((_Float16*)Cv)[(size_t)r * N + gn] = (_Float16)(acc[m][n][j] + bias[gn]);
        } else {
          ((_Float16*)Cv)[(size_t)r * N + gn] = (_Float16)acc[m][n][j];
        }
      }
    }
  }
}

// ---------------- small kernels ----------------
__global__ void k_f32_to_f16(const float* __restrict__ src, _Float16* __restrict__ dst, int n) {
  int i = blockIdx.x * 256 + threadIdx.x;
  if (i < n) dst[i] = (_Float16)src[i];
}

// We = W_ih[:, :768], Wc = W_ih[:, 768:1536]  (3072 x 768 each, f16)
__global__ void k_wih_split(const float* __restrict__ W_ih, _Float16* __restrict__ We,
                            _Float16* __restrict__ Wc) {
  int j = blockIdx.x;
  int k = blockIdx.y * 256 + threadIdx.x;
  We[(size_t)j * NH + k] = (_Float16)W_ih[(size_t)j * 1536 + k];
  Wc[(size_t)j * NH + k] = (_Float16)W_ih[(size_t)j * 1536 + 768 + k];
}

// W1 (3840 x 768) = [Wh (attn_W[:,768:]) ; W_hh]
__global__ void k_w1cat(const float* __restrict__ attn_W, const float* __restrict__ W_hh,
                        _Float16* __restrict__ W1) {
  int j = blockIdx.x;
  int k = blockIdx.y * 256 + threadIdx.x;
  float v = (j < NH) ? attn_W[(size_t)j * 1536 + 768 + k]
                     : W_hh[(size_t)(j - NH) * NH + k];
  W1[(size_t)j * NH + k] = (_Float16)v;
}

// emb16[t*128+b] = emb_W[captions[b,t]]  (f16)
__global__ void k_emb2(const int* __restrict__ captions, const float* __restrict__ emb_W,
                       _Float16* __restrict__ emb16) {
  int row = blockIdx.x;  // t*128+b
  int k = blockIdx.y * 256 + threadIdx.x;
  int t = row >> 7, b = row & 127;
  int tok = captions[b * NT + t];
  emb16[(size_t)row * NH + k] = (_Float16)emb_W[(size_t)tok * NH + k];
}

// h0 = tanh(mean_r features), c0 = 0
__global__ void k_init(const float* __restrict__ features, float* __restrict__ h,
                       float* __restrict__ c, _Float16* __restrict__ h16) {
  int b = blockIdx.x;
  int f = blockIdx.y * 256 + threadIdx.x;
  float s = 0.f;
#pragma unroll 7
  for (int r = 0; r < NR; r++) s += features[((size_t)(b * NR + r)) * NH + f];
  float h0 = tanhf(s * (1.f / 49.f));
  h[b * NH + f] = h0;
  c[b * NH + f] = 0.f;
  h16[(size_t)b * NH + f] = (_Float16)h0;
}

// scores[p] = v . tanh(fp_ready[p,:] + hw[b,:])  , p = b*49+r, one wave per p
__global__ __launch_bounds__(256) void k_scores(
    const _Float16* __restrict__ fp, const float* __restrict__ g1,
    const float* __restrict__ v, float* __restrict__ sc) {
  int wid = threadIdx.x >> 6, lane = threadIdx.x & 63;
  int p = blockIdx.x * 4 + wid;  // 6272 pairs = 1568 blocks * 4 waves
  int b = p / NR;
  const _Float16* fpr = fp + (size_t)p * NH;
  const float* hw0 = g1 + (size_t)b * 3840;
  const float* hw1 = g1 + (size_t)NB * 3840 + (size_t)b * 3840;
  float s = 0.f;
#pragma unroll
  for (int it = 0; it < 3; it++) {
    int h = it * 256 + lane * 4;
    f16x4 fv = *(const f16x4*)(fpr + h);
    f32x4 a0 = *(const f32x4*)(hw0 + h);
    f32x4 a1 = *(const f32x4*)(hw1 + h);
    f32x4 vv = *(const f32x4*)(v + h);
#pragma unroll
    for (int j = 0; j < 4; j++) s += fast_tanh((float)fv[j] + a0[j] + a1[j]) * vv[j];
  }
#pragma unroll
  for (int off = 32; off; off >>= 1) s += __shfl_down(s, off);
  if (lane == 0) sc[p] = s;
}

// softmax over r + context: ctx16[b, fchunk] ; grid (128, 3) x 256
__global__ __launch_bounds__(256) void k_ctx(const float* __restrict__ sc,
                                             const _Float16* __restrict__ feat16,
                                             _Float16* __restrict__ ctx16) {
  __shared__ float al[64];
  int b = blockIdx.x, tid = threadIdx.x;
  if (tid < 64) {
    float s = (tid < NR) ? sc[b * NR + tid] : -1e30f;
    float m = s;
#pragma unroll
    for (int off = 32; off; off >>= 1) m = fmaxf(m, __shfl_xor(m, off));
    float e = (tid < NR) ? __expf(s - m) : 0.f;
    float su = e;
#pragma unroll
    for (int off = 32; off; off >>= 1) su += __shfl_xor(su, off);
    al[tid] = e / su;
  }
  __syncthreads();
  int f = blockIdx.y * 256 + tid;
  const _Float16* fb = feat16 + (size_t)b * NR * NH + f;
  float acc = 0.f;
#pragma unroll
  for (int r = 0; r < NR; r++) acc += al[r] * (float)fb[(size_t)r * NH];
  ctx16[(size_t)b * NH + f] = (_Float16)acc;
}

// LSTM elementwise: gates = G_emb[t] + g1(h-part, 2 z) + g2(ctx-part, 2 z) + biases
__global__ void k_lstm2(const _Float16* __restrict__ ge_t, const float* __restrict__ g1,
                        const float* __restrict__ g2, const float* __restrict__ b_ih,
                        const float* __restrict__ b_hh, float* __restrict__ h,
                        float* __restrict__ c, _Float16* __restrict__ h16,
                        _Float16* __restrict__ Hall_t) {
  int b = blockIdx.x;
  int hh = blockIdx.y * 256 + threadIdx.x;
  const _Float16* ge = ge_t + (size_t)b * 3072;
  const float* a0 = g1 + (size_t)b * 3840 + 768;
  const float* a1 = g1 + (size_t)NB * 3840 + (size_t)b * 3840 + 768;
  const float* c0 = g2 + (size_t)b * 3072;
  const float* c1 = g2 + (size_t)NB * 3072 + (size_t)b * 3072;
  float gi = (float)ge[hh] + a0[hh] + a1[hh] + c0[hh] + c1[hh] + b_ih[hh] + b_hh[hh];
  float gf = (float)ge[768 + hh] + a0[768 + hh] + a1[768 + hh] + c0[768 + hh] + c1[768 + hh] +
             b_ih[768 + hh] + b_hh[768 + hh];
  float gg = (float)ge[1536 + hh] + a0[1536 + hh] + a1[1536 + hh] + c0[1536 + hh] +
             c1[1536 + hh] + b_ih[1536 + hh] + b_hh[1536 + hh];
  float go = (float)ge[2304 + hh] + a0[2304 + hh] + a1[2304 + hh] + c0[2304 + hh] +
             c1[2304 + hh] + b_ih[2304 + hh] + b_hh[2304 + hh];
  float i_ = sigm(gi), f_ = sigm(gf), g_ = fast_tanh(gg), o_ = sigm(go);
  float cn = f_ * c[b * NH + hh] + i_ * g_;
  float hn = o_ * fast_tanh(cn);
  c[b * NH + hh] = cn;
  h[b * NH + hh] = hn;
  h16[(size_t)b * NH + hh] = (_Float16)hn;
  Hall_t[(size_t)b * NH + hh] = (_Float16)hn;
}

__global__ void k_tail(const float* __restrict__ h, const float* __restrict__ c,
                       float* __restrict__ out) {
  int i = blockIdx.x * 256 + threadIdx.x;  // 98304
  out[OUT_ELEMS + i] = h[i];
  out[OUT_ELEMS + NB * NH + i] = c[i];
}

// ---------------- host ----------------
extern "C" void kernel_launch(void* const* d_in, const int* in_sizes, int n_in,
                              void* d_out, int out_size, void* d_ws, size_t ws_size,
                              hipStream_t stream) {
  const float* features = (const float*)d_in[0];
  const int* captions = (const int*)d_in[1];
  const float* emb_W = (const float*)d_in[2];
  const float* attn_W = (const float*)d_in[3];
  const float* attn_b = (const float*)d_in[4];
  const float* attnv_W = (const float*)d_in[5];
  // d_in[6] attnv_b: constant shift, cancels in softmax
  const float* W_ih = (const float*)d_in[7];
  const float* W_hh = (const float*)d_in[8];
  const float* b_ih = (const float*)d_in[9];
  const float* b_hh = (const float*)d_in[10];
  const float* fc_W = (const float*)d_in[11];
  const float* fc_b = (const float*)d_in[12];
  float* out = (float*)d_out;

  char* p = (char*)d_ws;
  _Float16* Gemb16 = (_Float16*)p;  p += 25165824;  // (4096,3072) f16 — aliased by fcW16 after loop
  _Float16* fcW16 = Gemb16;                         // (10000,768) f16, reuse after last lstm
  _Float16* emb16 = (_Float16*)p;   p += 6291456;   // (4096,768): row t*128+b
  _Float16* feat16 = (_Float16*)p;  p += 9633792;   // (6272,768)
  _Float16* fp16 = (_Float16*)p;    p += 9633792;   // feat_proj + attn_b (6272,768)
  _Float16* attnW16 = (_Float16*)p; p += 2359296;   // (768,1536)
  _Float16* W1 = (_Float16*)p;      p += 5898240;   // (3840,768): [Wh ; W_hh]
  _Float16* We16 = (_Float16*)p;    p += 4718592;   // (3072,768)
  _Float16* Wc16 = (_Float16*)p;    p += 4718592;   // (3072,768)
  _Float16* H_all = (_Float16*)p;   p += 6291456;   // (4096,768): row t*128+b
  float* g1 = (float*)p;            p += 3932160;   // 2 x (128,3840)
  float* g2 = (float*)p;            p += 3145728;   // 2 x (128,3072)
  float* scores = (float*)p;        p += 25088;     // (6272,)
  _Float16* ctx16 = (_Float16*)p;   p += 196608;    // (128,768)
  _Float16* h16 = (_Float16*)p;     p += 196608;    // (128,768)
  float* hbuf = (float*)p;          p += 393216;
  float* cbuf = (float*)p;          p += 393216;    // total ~83 MB

  // ---- phase A ----
  k_f32_to_f16<<<dim3(18816), 256, 0, stream>>>(features, feat16, 4816896);
  k_f32_to_f16<<<dim3(4608), 256, 0, stream>>>(attn_W, attnW16, 1179648);
  k_wih_split<<<dim3(3072, 3), 256, 0, stream>>>(W_ih, We16, Wc16);
  k_w1cat<<<dim3(3840, 3), 256, 0, stream>>>(attn_W, W_hh, W1);
  k_emb2<<<dim3(4096, 3), 256, 0, stream>>>(captions, emb_W, emb16);
  k_init<<<dim3(128, 3), 256, 0, stream>>>(features, hbuf, cbuf, h16);
  // fp16 = features @ Wf.T + attn_b   (6272x768, K=768)
  gemm_f16<128, 128, 3><<<dim3(49, 6, 1), 256, 0, stream>>>(
      feat16, 768, attnW16, 1536, fp16, attn_b, 6272, 768, 12, 0);
  // Gemb = emb @ We.T  (4096x3072, K=768), f16 out
  gemm_f16<128, 128, 4><<<dim3(32, 24, 1), 256, 0, stream>>>(
      emb16, 768, We16, 768, Gemb16, nullptr, 4096, 3072, 12, 0);

  // ---- sequential scan ----
  for (int t = 0; t < NT; t++) {
    if (t > 0)
      k_lstm2<<<dim3(128, 3), 256, 0, stream>>>(
          Gemb16 + (size_t)(t - 1) * NB * 3072, g1, g2, b_ih, b_hh, hbuf, cbuf, h16,
          H_all + (size_t)(t - 1) * NB * NH);
    // g1 = h @ [Wh ; W_hh].T  (128x3840, K=768, split-K 2)
    gemm_f16<64, 64, 1><<<dim3(2, 60, 2), 256, 0, stream>>>(
        h16, 768, W1, 768, g1, nullptr, 128, 3840, 6, 384);
    k_scores<<<dim3(1568), 256, 0, stream>>>(fp16, g1, attnv_W, scores);
    k_ctx<<<dim3(128, 3), 256, 0, stream>>>(scores, feat16, ctx16);
    // g2 = ctx @ Wc.T  (128x3072, K=768, split-K 2)
    gemm_f16<64, 64, 1><<<dim3(2, 48, 2), 256, 0, stream>>>(
        ctx16, 768, Wc16, 768, g2, nullptr, 128, 3072, 6, 384);
  }
  k_lstm2<<<dim3(128, 3), 256, 0, stream>>>(
      Gemb16 + (size_t)(NT - 1) * NB * 3072, g1, g2, b_ih, b_hh, hbuf, cbuf, h16,
      H_all + (size_t)(NT - 1) * NB * NH);

  // ---- fc (fcW16 aliases Gemb16, safe after last lstm in stream order) ----
  k_f32_to_f16<<<dim3(30000), 256, 0, stream>>>(fc_W, fcW16, 7680000);
  gemm_f16<128, 128, 2><<<dim3(32, 79, 1), 256, 0, stream>>>(
      H_all, 768, fcW16, 768, out, fc_b, 4096, 10000, 12, 0);
  k_tail<<<dim3(384), 256, 0, stream>>>(hbuf, cbuf, out);
}